// Round 7
// baseline (399.207 us; speedup 1.0000x reference)
//
#include <hip/hip_runtime.h>

#define LUT_D   33
#define LUT_D2  1089
#define LUT_D3  35937
#define HW      8294400
#define NLUT    8
#define NCELL   32768   // 32^3 cells per LUT

typedef float f4v __attribute__((ext_vector_type(4)));

__device__ __forceinline__ void softmax8(const float* __restrict__ lc, float* w)
{
    float m = lc[0];
#pragma unroll
    for (int n = 1; n < NLUT; ++n) m = fmaxf(m, lc[n]);
    float s = 0.f;
#pragma unroll
    for (int n = 0; n < NLUT; ++n) { w[n] = expf(lc[n] - m); s += w[n]; }
    float inv = 1.f / s;
#pragma unroll
    for (int n = 0; n < NLUT; ++n) w[n] *= inv;
}

// ---------------------------------------------------------------------------
// Pass 1: softmax-weighted combine, planar f32 output.
//   cg[l][c][idx] = sum_n w[l][n] * lut[l][n][c][idx]
// ---------------------------------------------------------------------------
__global__ void __launch_bounds__(256)
combine_grid(const float* __restrict__ lut,
             const float* __restrict__ lc0,
             const float* __restrict__ lc1,
             float* __restrict__ cg)
{
    int t = blockIdx.x * 256 + threadIdx.x;
    if (t >= 2 * 3 * LUT_D3) return;
    int l   = t / (3 * LUT_D3);
    int rem = t - l * 3 * LUT_D3;

    float w[NLUT];
    softmax8(l ? lc1 : lc0, w);

    const float* base = lut + (size_t)l * NLUT * 3 * LUT_D3 + rem;
    float a = 0.f;
#pragma unroll
    for (int n = 0; n < NLUT; ++n)
        a = fmaf(w[n], base[(size_t)n * 3 * LUT_D3], a);
    cg[t] = a;
}

// ---------------------------------------------------------------------------
// Pass 2: build cell tables.
//   LUT0 -> tab0: u16 cells, 24 vals in 48B packed, 64B-aligned slot.
//   LUT1 -> tab1: u10 cells, 32B slot: dword k = corner k (k=db*4+dg*2+dr),
//                 channels c0,c1,c2 at bits 0-9 / 10-19 / 20-29.
// ---------------------------------------------------------------------------
__global__ void __launch_bounds__(256)
cellify(const float* __restrict__ cg,
        uint4* __restrict__ tab0,
        uint4* __restrict__ tab1)
{
    int id = blockIdx.x * 256 + threadIdx.x;      // 0..65535
    int l    = id >> 15;
    int cell = id & (NCELL - 1);
    int ir = cell & 31, ig = (cell >> 5) & 31, ib = cell >> 10;

    const float* g0 = cg + (size_t)l * 3 * LUT_D3 + (ib * LUT_D + ig) * LUT_D + ir;

    float cv[24];   // cv[k*3+c]
#pragma unroll
    for (int c = 0; c < 3; ++c) {
        const float* p = g0 + (size_t)c * LUT_D3;
#pragma unroll
        for (int k = 0; k < 8; ++k) {
            int off = (k >> 2) * LUT_D2 + ((k >> 1) & 1) * LUT_D + (k & 1);
            cv[k * 3 + c] = p[off];
        }
    }

    if (l == 0) {
        unsigned pk[12];
#pragma unroll
        for (int j = 0; j < 12; ++j) {
            unsigned lo = (unsigned)(fminf(cv[2*j],   1.f) * 65535.f + 0.5f);
            unsigned hi = (unsigned)(fminf(cv[2*j+1], 1.f) * 65535.f + 0.5f);
            pk[j] = lo | (hi << 16);
        }
        uint4* dst = tab0 + (size_t)cell * 4;     // 64B slot
        dst[0] = make_uint4(pk[0], pk[1], pk[2],  pk[3]);
        dst[1] = make_uint4(pk[4], pk[5], pk[6],  pk[7]);
        dst[2] = make_uint4(pk[8], pk[9], pk[10], pk[11]);
    } else {
        unsigned d[8];
#pragma unroll
        for (int k = 0; k < 8; ++k) {
            unsigned e0 = (unsigned)(fminf(cv[3*k + 0], 1.f) * 1023.f + 0.5f);
            unsigned e1 = (unsigned)(fminf(cv[3*k + 1], 1.f) * 1023.f + 0.5f);
            unsigned e2 = (unsigned)(fminf(cv[3*k + 2], 1.f) * 1023.f + 0.5f);
            d[k] = e0 | (e1 << 10) | (e2 << 20);
        }
        uint4* dst = tab1 + (size_t)cell * 2;     // 32B slot
        dst[0] = make_uint4(d[0], d[1], d[2], d[3]);
        dst[1] = make_uint4(d[4], d[5], d[6], d[7]);
    }
}

// ---------------------------------------------------------------------------
// Stage 1: u16 cell (64B slot, 3 loads). Returns values scaled by 65535.
// ---------------------------------------------------------------------------
__device__ __forceinline__ void stage1(const uint4* __restrict__ tab,
                                       float xr, float xg, float xb,
                                       float& o0, float& o1, float& o2)
{
    int ir = min((int)xr, 31), ig = min((int)xg, 31), ib = min((int)xb, 31);
    float fr = xr - (float)ir, fg = xg - (float)ig, fb = xb - (float)ib;

    const uint4* p = tab + (size_t)((((ib << 5) | ig) << 5) | ir) * 4;
    uint4 q0 = p[0];
    uint4 q1 = p[1];
    uint4 q2 = p[2];

#define LOF(u) ((float)((u) & 0xffffu))
#define HIF(u) ((float)((u) >> 16))
    float k0c0=LOF(q0.x), k0c1=HIF(q0.x), k0c2=LOF(q0.y);
    float k1c0=HIF(q0.y), k1c1=LOF(q0.z), k1c2=HIF(q0.z);
    float k2c0=LOF(q0.w), k2c1=HIF(q0.w), k2c2=LOF(q1.x);
    float k3c0=HIF(q1.x), k3c1=LOF(q1.y), k3c2=HIF(q1.y);
    float k4c0=LOF(q1.z), k4c1=HIF(q1.z), k4c2=LOF(q1.w);
    float k5c0=HIF(q1.w), k5c1=LOF(q2.x), k5c2=HIF(q2.x);
    float k6c0=LOF(q2.y), k6c1=HIF(q2.y), k6c2=LOF(q2.z);
    float k7c0=HIF(q2.z), k7c1=LOF(q2.w), k7c2=HIF(q2.w);
#undef LOF
#undef HIF

    float m0c0 = fmaf(fr, k1c0 - k0c0, k0c0);
    float m0c1 = fmaf(fr, k1c1 - k0c1, k0c1);
    float m0c2 = fmaf(fr, k1c2 - k0c2, k0c2);
    float m1c0 = fmaf(fr, k3c0 - k2c0, k2c0);
    float m1c1 = fmaf(fr, k3c1 - k2c1, k2c1);
    float m1c2 = fmaf(fr, k3c2 - k2c2, k2c2);
    float m2c0 = fmaf(fr, k5c0 - k4c0, k4c0);
    float m2c1 = fmaf(fr, k5c1 - k4c1, k4c1);
    float m2c2 = fmaf(fr, k5c2 - k4c2, k4c2);
    float m3c0 = fmaf(fr, k7c0 - k6c0, k6c0);
    float m3c1 = fmaf(fr, k7c1 - k6c1, k6c1);
    float m3c2 = fmaf(fr, k7c2 - k6c2, k6c2);

    float wg0 = 1.f - fg, wb0 = 1.f - fb;
    float w00 = wb0 * wg0, w01 = wb0 * fg, w10 = fb * wg0, w11 = fb * fg;

    o0 = fmaf(w00, m0c0, fmaf(w01, m1c0, fmaf(w10, m2c0, w11 * m3c0)));
    o1 = fmaf(w00, m0c1, fmaf(w01, m1c1, fmaf(w10, m2c1, w11 * m3c1)));
    o2 = fmaf(w00, m0c2, fmaf(w01, m1c2, fmaf(w10, m2c2, w11 * m3c2)));
}

// ---------------------------------------------------------------------------
// Stage 2: u10 cell (32B slot, 2 loads). Returns values scaled by 1023.
// ---------------------------------------------------------------------------
__device__ __forceinline__ void stage2(const uint4* __restrict__ tab,
                                       float xr, float xg, float xb,
                                       float& o0, float& o1, float& o2)
{
    int ir = min((int)xr, 31), ig = min((int)xg, 31), ib = min((int)xb, 31);
    float fr = xr - (float)ir, fg = xg - (float)ig, fb = xb - (float)ib;

    const uint4* p = tab + (size_t)((((ib << 5) | ig) << 5) | ir) * 2;
    uint4 qa = p[0];
    uint4 qb = p[1];

#define F0(u) ((float)((u) & 1023u))
#define F1(u) ((float)(((u) >> 10) & 1023u))
#define F2(u) ((float)((u) >> 20))
    float m0c0 = fmaf(fr, F0(qa.y) - F0(qa.x), F0(qa.x));
    float m0c1 = fmaf(fr, F1(qa.y) - F1(qa.x), F1(qa.x));
    float m0c2 = fmaf(fr, F2(qa.y) - F2(qa.x), F2(qa.x));
    float m1c0 = fmaf(fr, F0(qa.w) - F0(qa.z), F0(qa.z));
    float m1c1 = fmaf(fr, F1(qa.w) - F1(qa.z), F1(qa.z));
    float m1c2 = fmaf(fr, F2(qa.w) - F2(qa.z), F2(qa.z));
    float m2c0 = fmaf(fr, F0(qb.y) - F0(qb.x), F0(qb.x));
    float m2c1 = fmaf(fr, F1(qb.y) - F1(qb.x), F1(qb.x));
    float m2c2 = fmaf(fr, F2(qb.y) - F2(qb.x), F2(qb.x));
    float m3c0 = fmaf(fr, F0(qb.w) - F0(qb.z), F0(qb.z));
    float m3c1 = fmaf(fr, F1(qb.w) - F1(qb.z), F1(qb.z));
    float m3c2 = fmaf(fr, F2(qb.w) - F2(qb.z), F2(qb.z));
#undef F0
#undef F1
#undef F2

    float wg0 = 1.f - fg, wb0 = 1.f - fb;
    float w00 = wb0 * wg0, w01 = wb0 * fg, w10 = fb * wg0, w11 = fb * fg;

    o0 = fmaf(w00, m0c0, fmaf(w01, m1c0, fmaf(w10, m2c0, w11 * m3c0)));
    o1 = fmaf(w00, m0c1, fmaf(w01, m1c1, fmaf(w10, m2c1, w11 * m3c1)));
    o2 = fmaf(w00, m0c2, fmaf(w01, m1c2, fmaf(w10, m2c2, w11 * m3c2)));
}

// ---------------------------------------------------------------------------
// Apply kernel: 1 lane per pixel, 4 pixels/thread, float4 non-temporal I/O.
// __launch_bounds__(256, 8): force VGPR <= 64 so 8 waves/SIMD fit.
// ---------------------------------------------------------------------------
__global__ void __launch_bounds__(256, 8)
lut_apply(const float* __restrict__ gt,
          const uint4* __restrict__ tab0,
          const uint4* __restrict__ tab1,
          float* __restrict__ out)
{
    int t = blockIdx.x * 256 + threadIdx.x;

    const f4v* Rp = (const f4v*)gt;
    const f4v* Gp = (const f4v*)(gt + HW);
    const f4v* Bp = (const f4v*)(gt + 2 * HW);
    f4v r4 = __builtin_nontemporal_load(Rp + t);
    f4v g4 = __builtin_nontemporal_load(Gp + t);
    f4v b4 = __builtin_nontemporal_load(Bp + t);

    f4v ro, go, bo;
#pragma unroll
    for (int k = 0; k < 4; ++k) {
        float xr = fminf(fmaxf(r4[k], 0.f), 1.f) * 32.f;
        float xg = fminf(fmaxf(g4[k], 0.f), 1.f) * 32.f;
        float xb = fminf(fmaxf(b4[k], 0.f), 1.f) * 32.f;

        float a0, a1, a2;
        stage1(tab0, xr, xg, xb, a0, a1, a2);

        // a* in [0, 65535] by construction (convex comb of u16) — no clamp.
        const float S = 32.f / 65535.f;
        float x2r = a0 * S;
        float x2g = a1 * S;
        float x2b = a2 * S;

        float b0, b1, b2;
        stage2(tab1, x2r, x2g, x2b, b0, b1, b2);

        const float I = 1.f / 1023.f;
        ro[k] = b0 * I;
        go[k] = b1 * I;
        bo[k] = b2 * I;
    }

    __builtin_nontemporal_store(ro, (f4v*)out + t);
    __builtin_nontemporal_store(go, (f4v*)(out + HW) + t);
    __builtin_nontemporal_store(bo, (f4v*)(out + 2 * HW) + t);
}

extern "C" void kernel_launch(void* const* d_in, const int* in_sizes, int n_in,
                              void* d_out, int out_size, void* d_ws, size_t ws_size,
                              hipStream_t stream)
{
    const float* gt  = (const float*)d_in[0];
    const float* lut = (const float*)d_in[1];
    const float* lc0 = (const float*)d_in[2];
    const float* lc1 = (const float*)d_in[3];
    float*       out = (float*)d_out;

    uint4* tab0 = (uint4*)d_ws;                                   // 2 MiB
    uint4* tab1 = (uint4*)((char*)d_ws + (size_t)NCELL * 64);     // 1 MiB
    float* cg   = (float*)((char*)d_ws + (size_t)NCELL * 96);     // 862,488 B

    int n1 = 2 * 3 * LUT_D3;                           // 215,622
    combine_grid<<<(n1 + 255) / 256, 256, 0, stream>>>(lut, lc0, lc1, cg);

    cellify<<<(2 * NCELL) / 256, 256, 0, stream>>>(cg, tab0, tab1);

    int nthreads = HW / 4;                             // 2,073,600
    lut_apply<<<nthreads / 256, 256, 0, stream>>>(gt, tab0, tab1, out);
}

// Round 8
// 261.499 us; speedup vs baseline: 1.5266x; 1.5266x over previous
//
#include <hip/hip_runtime.h>

#define LUT_D   33
#define LUT_D2  1089
#define LUT_D3  35937
#define HW      8294400
#define NLUT    8
#define NCELL   32768   // 32^3 cells per LUT

typedef float f4v __attribute__((ext_vector_type(4)));

__device__ __forceinline__ void softmax8(const float* __restrict__ lc, float* w)
{
    float m = lc[0];
#pragma unroll
    for (int n = 1; n < NLUT; ++n) m = fmaxf(m, lc[n]);
    float s = 0.f;
#pragma unroll
    for (int n = 0; n < NLUT; ++n) { w[n] = expf(lc[n] - m); s += w[n]; }
    float inv = 1.f / s;
#pragma unroll
    for (int n = 0; n < NLUT; ++n) w[n] *= inv;
}

// ---------------------------------------------------------------------------
// Pass 1: softmax-weighted combine, planar f32 output.
//   cg[l][c][idx] = sum_n w[l][n] * lut[l][n][c][idx]
// ---------------------------------------------------------------------------
__global__ void __launch_bounds__(256)
combine_grid(const float* __restrict__ lut,
             const float* __restrict__ lc0,
             const float* __restrict__ lc1,
             float* __restrict__ cg)
{
    int t = blockIdx.x * 256 + threadIdx.x;
    if (t >= 2 * 3 * LUT_D3) return;
    int l   = t / (3 * LUT_D3);
    int rem = t - l * 3 * LUT_D3;

    float w[NLUT];
    softmax8(l ? lc1 : lc0, w);

    const float* base = lut + (size_t)l * NLUT * 3 * LUT_D3 + rem;
    float a = 0.f;
#pragma unroll
    for (int n = 0; n < NLUT; ++n)
        a = fmaf(w[n], base[(size_t)n * 3 * LUT_D3], a);
    cg[t] = a;
}

// ---------------------------------------------------------------------------
// Pass 2: build cell tables.
//   LUT0 -> tab0: u16 cells, 24 vals in 48B packed, 64B-aligned slot.
//   LUT1 -> tab1: u10 cells, 32B slot: dword k = corner k (k=db*4+dg*2+dr),
//                 channels c0,c1,c2 at bits 0-9 / 10-19 / 20-29.
// ---------------------------------------------------------------------------
__global__ void __launch_bounds__(256)
cellify(const float* __restrict__ cg,
        uint4* __restrict__ tab0,
        uint4* __restrict__ tab1)
{
    int id = blockIdx.x * 256 + threadIdx.x;      // 0..65535
    int l    = id >> 15;
    int cell = id & (NCELL - 1);
    int ir = cell & 31, ig = (cell >> 5) & 31, ib = cell >> 10;

    const float* g0 = cg + (size_t)l * 3 * LUT_D3 + (ib * LUT_D + ig) * LUT_D + ir;

    float cv[24];   // cv[k*3+c]
#pragma unroll
    for (int c = 0; c < 3; ++c) {
        const float* p = g0 + (size_t)c * LUT_D3;
#pragma unroll
        for (int k = 0; k < 8; ++k) {
            int off = (k >> 2) * LUT_D2 + ((k >> 1) & 1) * LUT_D + (k & 1);
            cv[k * 3 + c] = p[off];
        }
    }

    if (l == 0) {
        unsigned pk[12];
#pragma unroll
        for (int j = 0; j < 12; ++j) {
            unsigned lo = (unsigned)(fminf(cv[2*j],   1.f) * 65535.f + 0.5f);
            unsigned hi = (unsigned)(fminf(cv[2*j+1], 1.f) * 65535.f + 0.5f);
            pk[j] = lo | (hi << 16);
        }
        uint4* dst = tab0 + (size_t)cell * 4;     // 64B slot
        dst[0] = make_uint4(pk[0], pk[1], pk[2],  pk[3]);
        dst[1] = make_uint4(pk[4], pk[5], pk[6],  pk[7]);
        dst[2] = make_uint4(pk[8], pk[9], pk[10], pk[11]);
    } else {
        unsigned d[8];
#pragma unroll
        for (int k = 0; k < 8; ++k) {
            unsigned e0 = (unsigned)(fminf(cv[3*k + 0], 1.f) * 1023.f + 0.5f);
            unsigned e1 = (unsigned)(fminf(cv[3*k + 1], 1.f) * 1023.f + 0.5f);
            unsigned e2 = (unsigned)(fminf(cv[3*k + 2], 1.f) * 1023.f + 0.5f);
            d[k] = e0 | (e1 << 10) | (e2 << 20);
        }
        uint4* dst = tab1 + (size_t)cell * 2;     // 32B slot
        dst[0] = make_uint4(d[0], d[1], d[2], d[3]);
        dst[1] = make_uint4(d[4], d[5], d[6], d[7]);
    }
}

// ---------------------------------------------------------------------------
// Stage 1: u16 cell (64B slot, 3 loads). Returns values scaled by 65535.
// ---------------------------------------------------------------------------
__device__ __forceinline__ void stage1(const uint4* __restrict__ tab,
                                       float xr, float xg, float xb,
                                       float& o0, float& o1, float& o2)
{
    int ir = min((int)xr, 31), ig = min((int)xg, 31), ib = min((int)xb, 31);
    float fr = xr - (float)ir, fg = xg - (float)ig, fb = xb - (float)ib;

    const uint4* p = tab + (size_t)((((ib << 5) | ig) << 5) | ir) * 4;
    uint4 q0 = p[0];
    uint4 q1 = p[1];
    uint4 q2 = p[2];

#define LOF(u) ((float)((u) & 0xffffu))
#define HIF(u) ((float)((u) >> 16))
    float k0c0=LOF(q0.x), k0c1=HIF(q0.x), k0c2=LOF(q0.y);
    float k1c0=HIF(q0.y), k1c1=LOF(q0.z), k1c2=HIF(q0.z);
    float k2c0=LOF(q0.w), k2c1=HIF(q0.w), k2c2=LOF(q1.x);
    float k3c0=HIF(q1.x), k3c1=LOF(q1.y), k3c2=HIF(q1.y);
    float k4c0=LOF(q1.z), k4c1=HIF(q1.z), k4c2=LOF(q1.w);
    float k5c0=HIF(q1.w), k5c1=LOF(q2.x), k5c2=HIF(q2.x);
    float k6c0=LOF(q2.y), k6c1=HIF(q2.y), k6c2=LOF(q2.z);
    float k7c0=HIF(q2.z), k7c1=LOF(q2.w), k7c2=HIF(q2.w);
#undef LOF
#undef HIF

    float m0c0 = fmaf(fr, k1c0 - k0c0, k0c0);
    float m0c1 = fmaf(fr, k1c1 - k0c1, k0c1);
    float m0c2 = fmaf(fr, k1c2 - k0c2, k0c2);
    float m1c0 = fmaf(fr, k3c0 - k2c0, k2c0);
    float m1c1 = fmaf(fr, k3c1 - k2c1, k2c1);
    float m1c2 = fmaf(fr, k3c2 - k2c2, k2c2);
    float m2c0 = fmaf(fr, k5c0 - k4c0, k4c0);
    float m2c1 = fmaf(fr, k5c1 - k4c1, k4c1);
    float m2c2 = fmaf(fr, k5c2 - k4c2, k4c2);
    float m3c0 = fmaf(fr, k7c0 - k6c0, k6c0);
    float m3c1 = fmaf(fr, k7c1 - k6c1, k6c1);
    float m3c2 = fmaf(fr, k7c2 - k6c2, k6c2);

    float wg0 = 1.f - fg, wb0 = 1.f - fb;
    float w00 = wb0 * wg0, w01 = wb0 * fg, w10 = fb * wg0, w11 = fb * fg;

    o0 = fmaf(w00, m0c0, fmaf(w01, m1c0, fmaf(w10, m2c0, w11 * m3c0)));
    o1 = fmaf(w00, m0c1, fmaf(w01, m1c1, fmaf(w10, m2c1, w11 * m3c1)));
    o2 = fmaf(w00, m0c2, fmaf(w01, m1c2, fmaf(w10, m2c2, w11 * m3c2)));
}

// ---------------------------------------------------------------------------
// Stage 2: u10 cell (32B slot, 2 loads). Returns values scaled by 1023.
// ---------------------------------------------------------------------------
__device__ __forceinline__ void stage2(const uint4* __restrict__ tab,
                                       float xr, float xg, float xb,
                                       float& o0, float& o1, float& o2)
{
    int ir = min((int)xr, 31), ig = min((int)xg, 31), ib = min((int)xb, 31);
    float fr = xr - (float)ir, fg = xg - (float)ig, fb = xb - (float)ib;

    const uint4* p = tab + (size_t)((((ib << 5) | ig) << 5) | ir) * 2;
    uint4 qa = p[0];
    uint4 qb = p[1];

#define F0(u) ((float)((u) & 1023u))
#define F1(u) ((float)(((u) >> 10) & 1023u))
#define F2(u) ((float)((u) >> 20))
    float m0c0 = fmaf(fr, F0(qa.y) - F0(qa.x), F0(qa.x));
    float m0c1 = fmaf(fr, F1(qa.y) - F1(qa.x), F1(qa.x));
    float m0c2 = fmaf(fr, F2(qa.y) - F2(qa.x), F2(qa.x));
    float m1c0 = fmaf(fr, F0(qa.w) - F0(qa.z), F0(qa.z));
    float m1c1 = fmaf(fr, F1(qa.w) - F1(qa.z), F1(qa.z));
    float m1c2 = fmaf(fr, F2(qa.w) - F2(qa.z), F2(qa.z));
    float m2c0 = fmaf(fr, F0(qb.y) - F0(qb.x), F0(qb.x));
    float m2c1 = fmaf(fr, F1(qb.y) - F1(qb.x), F1(qb.x));
    float m2c2 = fmaf(fr, F2(qb.y) - F2(qb.x), F2(qb.x));
    float m3c0 = fmaf(fr, F0(qb.w) - F0(qb.z), F0(qb.z));
    float m3c1 = fmaf(fr, F1(qb.w) - F1(qb.z), F1(qb.z));
    float m3c2 = fmaf(fr, F2(qb.w) - F2(qb.z), F2(qb.z));
#undef F0
#undef F1
#undef F2

    float wg0 = 1.f - fg, wb0 = 1.f - fb;
    float w00 = wb0 * wg0, w01 = wb0 * fg, w10 = fb * wg0, w11 = fb * fg;

    o0 = fmaf(w00, m0c0, fmaf(w01, m1c0, fmaf(w10, m2c0, w11 * m3c0)));
    o1 = fmaf(w00, m0c1, fmaf(w01, m1c1, fmaf(w10, m2c1, w11 * m3c1)));
    o2 = fmaf(w00, m0c2, fmaf(w01, m1c2, fmaf(w10, m2c2, w11 * m3c2)));
}

// ---------------------------------------------------------------------------
// Apply kernel: 1 lane per pixel, 4 pixels/thread, float4 non-temporal I/O.
// NOTE: no min-waves clause — __launch_bounds__(256,8) forced VGPR=32 and
// spilled to scratch (R7: FETCH 57->357MB, WRITE 97->486MB, 2.1x slower).
// Natural footprint is ~60 VGPR; let the compiler have it.
// ---------------------------------------------------------------------------
__global__ void __launch_bounds__(256)
lut_apply(const float* __restrict__ gt,
          const uint4* __restrict__ tab0,
          const uint4* __restrict__ tab1,
          float* __restrict__ out)
{
    int t = blockIdx.x * 256 + threadIdx.x;

    const f4v* Rp = (const f4v*)gt;
    const f4v* Gp = (const f4v*)(gt + HW);
    const f4v* Bp = (const f4v*)(gt + 2 * HW);
    f4v r4 = __builtin_nontemporal_load(Rp + t);
    f4v g4 = __builtin_nontemporal_load(Gp + t);
    f4v b4 = __builtin_nontemporal_load(Bp + t);

    f4v ro, go, bo;
#pragma unroll
    for (int k = 0; k < 4; ++k) {
        float xr = fminf(fmaxf(r4[k], 0.f), 1.f) * 32.f;
        float xg = fminf(fmaxf(g4[k], 0.f), 1.f) * 32.f;
        float xb = fminf(fmaxf(b4[k], 0.f), 1.f) * 32.f;

        float a0, a1, a2;
        stage1(tab0, xr, xg, xb, a0, a1, a2);

        // a* in [0, 65535] by construction (convex comb of u16) — no clamp.
        const float S = 32.f / 65535.f;
        float x2r = a0 * S;
        float x2g = a1 * S;
        float x2b = a2 * S;

        float b0, b1, b2;
        stage2(tab1, x2r, x2g, x2b, b0, b1, b2);

        const float I = 1.f / 1023.f;
        ro[k] = b0 * I;
        go[k] = b1 * I;
        bo[k] = b2 * I;
    }

    __builtin_nontemporal_store(ro, (f4v*)out + t);
    __builtin_nontemporal_store(go, (f4v*)(out + HW) + t);
    __builtin_nontemporal_store(bo, (f4v*)(out + 2 * HW) + t);
}

extern "C" void kernel_launch(void* const* d_in, const int* in_sizes, int n_in,
                              void* d_out, int out_size, void* d_ws, size_t ws_size,
                              hipStream_t stream)
{
    const float* gt  = (const float*)d_in[0];
    const float* lut = (const float*)d_in[1];
    const float* lc0 = (const float*)d_in[2];
    const float* lc1 = (const float*)d_in[3];
    float*       out = (float*)d_out;

    uint4* tab0 = (uint4*)d_ws;                                   // 2 MiB
    uint4* tab1 = (uint4*)((char*)d_ws + (size_t)NCELL * 64);     // 1 MiB
    float* cg   = (float*)((char*)d_ws + (size_t)NCELL * 96);     // 862,488 B

    int n1 = 2 * 3 * LUT_D3;                           // 215,622
    combine_grid<<<(n1 + 255) / 256, 256, 0, stream>>>(lut, lc0, lc1, cg);

    cellify<<<(2 * NCELL) / 256, 256, 0, stream>>>(cg, tab0, tab1);

    int nthreads = HW / 4;                             // 2,073,600
    lut_apply<<<nthreads / 256, 256, 0, stream>>>(gt, tab0, tab1, out);
}